// Round 7
// baseline (261.121 us; speedup 1.0000x reference)
//
#include <hip/hip_runtime.h>
#include <stdint.h>

#define SQ 2048
#define DH 64
#define BH 64  // B*H

typedef __attribute__((ext_vector_type(8))) short bf16x8;
typedef __attribute__((ext_vector_type(4))) short bf16x4;
typedef __attribute__((ext_vector_type(4))) float f32x4;

// RNE f32->bf16 (Q only; one-time cost)
static __device__ __forceinline__ unsigned short f2bf_rne(float x) {
  union { float f; uint32_t u; } v; v.f = x;
  uint32_t u = v.u;
  return (unsigned short)((u + 0x7FFFu + ((u >> 16) & 1u)) >> 16);
}

// low16 = bf16_trunc(a), high16 = bf16_trunc(b) -- single v_perm_b32
static __device__ __forceinline__ uint32_t pack_hi(float a, float b) {
  uint32_t au = __float_as_uint(a), bu = __float_as_uint(b);
#if __has_builtin(__builtin_amdgcn_perm)
  return __builtin_amdgcn_perm(bu, au, 0x07060302u);
#else
  return (bu & 0xFFFF0000u) | (au >> 16);
#endif
}

// pack+mask fused: sel bytes 0x02,0x03 pick a's high half; 0x06,0x07 pick b's;
// 0x0C -> constant 0x00 (masked). v_perm sel 8..11 are sign-replicate; 12 is zero.
static __device__ __forceinline__ uint32_t pack_sel(float a, float b, uint32_t sel) {
#if __has_builtin(__builtin_amdgcn_perm)
  return __builtin_amdgcn_perm(__float_as_uint(b), __float_as_uint(a), sel);
#else
  uint32_t r = 0;
  uint64_t src = ((uint64_t)__float_as_uint(b) << 32) | __float_as_uint(a);
  for (int i = 0; i < 4; ++i) {
    uint32_t sb = (sel >> (8 * i)) & 0xFF;
    uint32_t byte = (sb < 8) ? (uint32_t)((src >> (8 * sb)) & 0xFF) : 0u;
    r |= byte << (8 * i);
  }
  return r;
#endif
}

static __device__ __forceinline__ float fast_exp2(float x) {
#if __has_builtin(__builtin_amdgcn_exp2f)
  return __builtin_amdgcn_exp2f(x);
#else
  return exp2f(x);
#endif
}

#define MFMA32(a, b, c) __builtin_amdgcn_mfma_f32_16x16x32_bf16((a), (b), (c), 0, 0, 0)
#if __has_builtin(__builtin_amdgcn_mfma_f32_16x16x16_bf16)
#define MFMA_PV16(a, b, c) __builtin_amdgcn_mfma_f32_16x16x16_bf16((a), (b), (c), 0, 0, 0)
#else
#define MFMA_PV16(a, b, c) __builtin_amdgcn_mfma_f32_16x16x16bf16_1k((a), (b), (c), 0, 0, 0)
#endif

// async global->LDS staging, width 16 (lane-contiguous dest layout required)
static __device__ __forceinline__ void stage16(const uint8_t* g, uint8_t* l) {
#if __has_builtin(__builtin_amdgcn_global_load_lds)
  __builtin_amdgcn_global_load_lds(
      (const __attribute__((address_space(1))) uint32_t*)g,
      (__attribute__((address_space(3))) uint32_t*)l, 16, 0, 0);
#else
  *(uint4*)l = *(const uint4*)g;
#endif
}

// kk permutation: phys row p holds logical kk L(p) so that QK C/D fragments
// concatenate directly into the K=32 PV B-operand.
// L(p) = (p&0x20) | ((p&0x0C)<<1) | ((p&0x10)>>2) | (p&3)

// ============================ merged pack kernel ============================
// blocks [0,2048): K/V bf16 pre-pack, LDS-image XOR-swizzled layouts.
//   K: per (bh,tile): 64 phys rows (logical row L(p)) x 8 chunks of 8 bf16;
//      physical chunk slot cp holds logical d-chunk c = cp ^ (p&7).
//   V: per (bh,tile): V^T rows d=0..63, 8 chunks of 8 consecutive logical kk
//      (bf16 pairs), physical slot cp = c ^ (d&7).
// blocks [2048,6144): mask -> v_perm selector words, kk-permuted to match K.
__global__ __launch_bounds__(256) void pack_all(const float* __restrict__ K,
                                                const float* __restrict__ V,
                                                const int* __restrict__ mask,
                                                uint4* __restrict__ pk,
                                                uint4* __restrict__ pv,
                                                uint2* __restrict__ pm) {
  const int t = threadIdx.x;
  if (blockIdx.x < 2048) {
    __shared__ uint32_t Vw[64][33];
    const int bt = blockIdx.x;  // bh*32 + tile
    // ---- K: permuted rows, swizzled chunks ----
    {
      const float* src = K + (size_t)bt * 64 * DH;
      uint4* dst = pk + (size_t)bt * 512;
#pragma unroll
      for (int j = 0; j < 2; ++j) {
        int i = t + j * 256;
        int p = i >> 3, cp = i & 7;
        int c = cp ^ (p & 7);
        int lkk = (p & 0x20) | ((p & 0x0C) << 1) | ((p & 0x10) >> 2) | (p & 3);
        const float4* s4 = (const float4*)(src + (size_t)lkk * DH + c * 8);
        float4 a = s4[0], b = s4[1];
        uint4 w;
        w.x = pack_hi(a.x, a.y); w.y = pack_hi(a.z, a.w);
        w.z = pack_hi(b.x, b.y); w.w = pack_hi(b.z, b.w);
        dst[i] = w;
      }
    }
    // ---- V: coalesced read, LDS transpose, chunked+swizzled write ----
    {
      const float* src = V + (size_t)bt * 64 * DH;
#pragma unroll
      for (int half = 0; half < 2; ++half) {
        int kp = (t >> 4) + half * 16;  // kk pair 0..31
        int d4 = (t & 15) * 4;
        float4 a = *(const float4*)(src + (size_t)(2 * kp) * DH + d4);
        float4 b = *(const float4*)(src + (size_t)(2 * kp + 1) * DH + d4);
        Vw[d4 + 0][kp] = pack_hi(a.x, b.x);
        Vw[d4 + 1][kp] = pack_hi(a.y, b.y);
        Vw[d4 + 2][kp] = pack_hi(a.z, b.z);
        Vw[d4 + 3][kp] = pack_hi(a.w, b.w);
      }
      __syncthreads();
      uint4* dst = pv + (size_t)bt * 512;
#pragma unroll
      for (int j = 0; j < 2; ++j) {
        int o = t + j * 256;
        int d = o >> 3, cp = o & 7;
        int c = cp ^ (d & 7);
        uint4 w;
        w.x = Vw[d][4 * c + 0]; w.y = Vw[d][4 * c + 1];
        w.z = Vw[d][4 * c + 2]; w.w = Vw[d][4 * c + 3];
        dst[o] = w;
      }
    }
  } else {
    __shared__ uint2 Lm[16][17];
    const int bid = blockIdx.x - 2048;
    const int qb = bid >> 5, gb = bid & 31;
    {
      int qq = t >> 4, gg = t & 15;  // gg = kt*4 + quad
      // permuted logical base for phys rows (kt,quad,r=0..3)
      int off = ((gg >> 3) << 5) | ((gg & 3) << 3) | (gg & 4);
      int4 m = *(const int4*)(mask + (size_t)(qb * 16 + qq) * SQ + gb * 64 + off);
      uint2 w;
      w.x = (m.x ? 0x00000C0Cu : 0x00000302u) | (m.y ? 0x0C0C0000u : 0x07060000u);
      w.y = (m.z ? 0x00000C0Cu : 0x00000302u) | (m.w ? 0x0C0C0000u : 0x07060000u);
      Lm[gg][qq] = w;
    }
    __syncthreads();
    {
      int gg = t >> 4, qq = t & 15;
      pm[(size_t)(gb * 16 + gg) * 2048 + qb * 16 + qq] = Lm[gg][qq];
    }
  }
}

// Bitmask for fallback path
__global__ void pack_mask_kernel(const int* __restrict__ mask,
                                 unsigned long long* __restrict__ bits) {
  const int lane = threadIdx.x & 63;
  const int gw = (blockIdx.x * blockDim.x + threadIdx.x) >> 6;
  const int nw = (gridDim.x * blockDim.x) >> 6;
  for (int w = gw; w < SQ * SQ / 64; w += nw) {
    int v = mask[(size_t)w * 64 + lane];
    unsigned long long b = __ballot(v != 0);
    if (lane == 0) bits[(size_t)(w & 31) * SQ + (w >> 5)] = b;
  }
}

// ============================ main kernel ============================
// Flash attention, S^T = K*Q^T, no-max exp2-domain softmax, prepacked K/V/mask
// with kk-permutation so PV runs as 16x16x32 (K=32). Wave owns 64 q. Optional
// kk-split (ntiles=16, grid 1024): writes unnormalized O-partial + l-partial.
__global__ __launch_bounds__(256, 2) void attn4(
    const uint8_t* __restrict__ pk, const uint8_t* __restrict__ pv,
    const uint2* __restrict__ pm, const float* __restrict__ Qg,
    float* __restrict__ opart, float* __restrict__ lpart, int ntiles) {
  // [0,8K) K buf0, [8K,16K) K buf1, [16K,24K) V buf0, [24K,32K) V buf1
  __shared__ __align__(16) uint8_t smem[32768];

  const int id = blockIdx.x;
  const int bh = id & 63;
  const int qblk = (id >> 6) & 7;
  const int split = id >> 9;           // 0 unless split grid
  const int tile0 = split * ntiles;
  const int t = threadIdx.x;
  const int wave = t >> 6, lane = t & 63, col = lane & 15, quad = lane >> 4;

  const float* Qb = Qg + (size_t)bh * SQ * DH;
  const uint8_t* pkb = pk + ((size_t)bh * 32 + tile0) * 8192;
  const uint8_t* pvb = pv + ((size_t)bh * 32 + tile0) * 8192;
  const int q0 = qblk * 256 + wave * 64;

  // Q fragments, scale 1/8 * log2(e) folded in (scores emerge in log2 domain)
  const float QSCALE = 0.18033688011112042f;
  bf16x8 qf[4][2];
#pragma unroll
  for (int s = 0; s < 4; ++s) {
    int q = q0 + s * 16 + col;
#pragma unroll
    for (int j = 0; j < 2; ++j) {
      const float4* p = (const float4*)(Qb + (size_t)q * DH + j * 32 + quad * 8);
      float4 a = p[0], b = p[1];
      bf16x8 f;
      f[0] = (short)f2bf_rne(a.x * QSCALE); f[1] = (short)f2bf_rne(a.y * QSCALE);
      f[2] = (short)f2bf_rne(a.z * QSCALE); f[3] = (short)f2bf_rne(a.w * QSCALE);
      f[4] = (short)f2bf_rne(b.x * QSCALE); f[5] = (short)f2bf_rne(b.y * QSCALE);
      f[6] = (short)f2bf_rne(b.z * QSCALE); f[7] = (short)f2bf_rne(b.w * QSCALE);
      qf[s][j] = f;
    }
  }

  // loop-invariant LDS byte offsets (XOR swizzle folded into lane constants)
  const unsigned ka0 = col * 128 + ((quad ^ (col & 7)) * 16);
  const unsigned ka1 = col * 128 + (((4 + quad) ^ (col & 7)) * 16);
  unsigned va[2];
#pragma unroll
  for (int ktp = 0; ktp < 2; ++ktp)
    va[ktp] = 16384u + col * 128 + (((ktp * 4 + quad) ^ (col & 7)) * 16);
  const unsigned stOff = (unsigned)t * 16;
  const char* pmt = (const char*)pm +
                    ((size_t)(tile0 * 16 + quad) * 2048 + q0 + col) * 8;

  f32x4 acc[4][4];  // O^T: row(d_local)=quad*4+r, col=q_local
  f32x4 accl[4];    // ones-MFMA row-sum
#pragma unroll
  for (int s = 0; s < 4; ++s) {
#pragma unroll
    for (int dt = 0; dt < 4; ++dt)
#pragma unroll
      for (int r = 0; r < 4; ++r) acc[s][dt][r] = 0.0f;
#pragma unroll
    for (int r = 0; r < 4; ++r) accl[s][r] = 0.0f;
  }
  bf16x8 vones8;
#pragma unroll
  for (int i = 0; i < 8; ++i) vones8[i] = (short)0x3F80;
  const f32x4 fz = {0.0f, 0.0f, 0.0f, 0.0f};

  // prologue: stage first tile into buf 0 (async direct-to-LDS)
  stage16(pkb + stOff, smem + stOff);
  stage16(pkb + 4096 + stOff, smem + 4096 + stOff);
  stage16(pvb + stOff, smem + 16384 + stOff);
  stage16(pvb + 4096 + stOff, smem + 20480 + stOff);
  unsigned buf = 0;

  for (int tt = 0; tt < ntiles; ++tt) {
    __syncthreads();  // drains staging (vmcnt) + syncs buffer reuse
    const int tl = (tt + 1 < ntiles) ? tt + 1 : tt;
    const uint8_t* pkt = pkb + (size_t)tl * 8192;
    const uint8_t* pvt = pvb + (size_t)tl * 8192;
    const unsigned ob = buf ^ 8192u;
    stage16(pkt + stOff, smem + ob + stOff);
    stage16(pkt + 4096 + stOff, smem + ob + 4096 + stOff);
    stage16(pvt + stOff, smem + 16384 + ob + stOff);
    stage16(pvt + 4096 + stOff, smem + 16384 + ob + 4096 + stOff);

    const char* pmc = pmt + (size_t)tt * 262144;
#pragma unroll
    for (int ktp = 0; ktp < 2; ++ktp) {
      // ---- QK^T for the two 16-row phys blocks of this ktp ----
      uint32_t pf[4][2][2];  // [s][kh][word]
#pragma unroll
      for (int kh = 0; kh < 2; ++kh) {
        const int kt = ktp * 2 + kh;
        const bf16x8 kf0 = *(const bf16x8*)(smem + buf + kt * 2048 + ka0);
        const bf16x8 kf1 = *(const bf16x8*)(smem + buf + kt * 2048 + ka1);
        uint2 mw[4];
#pragma unroll
        for (int s = 0; s < 4; ++s)
          mw[s] = *(const uint2*)(pmc + (size_t)kt * 65536 + s * 128);
#pragma unroll
        for (int s = 0; s < 4; ++s) {
          f32x4 st = MFMA32(kf0, qf[s][0], fz);
          st = MFMA32(kf1, qf[s][1], st);
          float p0 = fast_exp2(st[0]), p1 = fast_exp2(st[1]);
          float p2 = fast_exp2(st[2]), p3 = fast_exp2(st[3]);
          pf[s][kh][0] = pack_sel(p0, p1, mw[s].x);
          pf[s][kh][1] = pack_sel(p2, p3, mw[s].y);
        }
      }
      // ---- PV (K=32): O^T[d][q] += V^T[d][kk]*P^T[kk][q] ----
      union { uint4 u; bf16x8 v; } vf[4];
#pragma unroll
      for (int dt = 0; dt < 4; ++dt)
        vf[dt].u = *(const uint4*)(smem + buf + dt * 2048 + va[ktp]);
#pragma unroll
      for (int s = 0; s < 4; ++s) {
        union { uint32_t u[4]; bf16x8 v; } pw;
        pw.u[0] = pf[s][0][0]; pw.u[1] = pf[s][0][1];
        pw.u[2] = pf[s][1][0]; pw.u[3] = pf[s][1][1];
        accl[s] = MFMA32(vones8, pw.v, accl[s]);
#pragma unroll
        for (int dt = 0; dt < 4; ++dt)
          acc[s][dt] = MFMA32(vf[dt].v, pw.v, acc[s][dt]);
      }
    }
    buf = ob;
  }

  // ---- epilogue ----
  if (lpart) {
    float* obase = opart + ((size_t)split * BH + bh) * SQ * DH;
    float* lbase = lpart + (size_t)split * BH * SQ + (size_t)bh * SQ;
#pragma unroll
    for (int s = 0; s < 4; ++s) {
      int q = q0 + s * 16 + col;
      float* orow = obase + (size_t)q * DH;
#pragma unroll
      for (int dt = 0; dt < 4; ++dt) {
        float4 o;
        o.x = acc[s][dt][0]; o.y = acc[s][dt][1];
        o.z = acc[s][dt][2]; o.w = acc[s][dt][3];
        *(float4*)(orow + dt * 16 + quad * 4) = o;
      }
      if (quad == 0) lbase[q] = accl[s][0];
    }
  } else {
    float* obase = opart + (size_t)bh * SQ * DH;
#pragma unroll
    for (int s = 0; s < 4; ++s) {
      float inv = 1.0f / accl[s][0];
      int q = q0 + s * 16 + col;
      float* orow = obase + (size_t)q * DH;
#pragma unroll
      for (int dt = 0; dt < 4; ++dt) {
        float4 o;
        o.x = acc[s][dt][0] * inv; o.y = acc[s][dt][1] * inv;
        o.z = acc[s][dt][2] * inv; o.w = acc[s][dt][3] * inv;
        *(float4*)(orow + dt * 16 + quad * 4) = o;
      }
    }
  }
}

// merge the 2 kk-split partials: out = (P0+P1)/(l0+l1)
__global__ __launch_bounds__(256) void norm_kernel(const float4* __restrict__ p,
                                                   const float* __restrict__ l,
                                                   float4* __restrict__ out) {
  const size_t N4 = (size_t)BH * SQ * DH / 4;  // 2,097,152
  size_t i = (size_t)blockIdx.x * 256 + threadIdx.x;
  const size_t stride = (size_t)gridDim.x * 256;
  for (; i < N4; i += stride) {
    size_t ql = i >> 4;  // (i*4)/64
    float inv = 1.0f / (l[ql] + l[(size_t)BH * SQ + ql]);
    float4 a = p[i], b = p[N4 + i];
    float4 o;
    o.x = (a.x + b.x) * inv; o.y = (a.y + b.y) * inv;
    o.z = (a.z + b.z) * inv; o.w = (a.w + b.w) * inv;
    out[i] = o;
  }
}

// ============================ fallback kernel ============================
__global__ __launch_bounds__(512, 4) void attn_fb(
    const float* __restrict__ Qg, const float* __restrict__ Kg,
    const float* __restrict__ Vg, const unsigned long long* __restrict__ mbits,
    const int* __restrict__ mraw, float* __restrict__ Og) {
  __shared__ __align__(16) unsigned short Klds[2][64][72];
  __shared__ __align__(16) uint32_t Vtlds[2][64][36];
  const int id = blockIdx.x;
  const int bh = id & 63;
  const int qblk = id >> 6;
  const int t = threadIdx.x;
  const int wave = t >> 6, lane = t & 63, col = lane & 15, quad = lane >> 4;
  const float* Qb = Qg + (size_t)bh * SQ * DH;
  const float* Kb = Kg + (size_t)bh * SQ * DH;
  const float* Vb = Vg + (size_t)bh * SQ * DH;
  float* Ob = Og + (size_t)bh * SQ * DH;
  const int q0 = qblk * 256 + wave * 32;
  const int skk = t >> 3, sd8 = (t & 7) * 8, skp = t >> 4, sd4 = (t & 15) * 4;
  const float QSCALE = 0.18033688011112042f;
  bf16x8 qf[2][2];
#pragma unroll
  for (int s = 0; s < 2; ++s) {
    int q = q0 + s * 16 + col;
#pragma unroll
    for (int j = 0; j < 2; ++j) {
      const float4* p = (const float4*)(Qb + (size_t)q * DH + j * 32 + quad * 8);
      float4 a = p[0], b = p[1];
      bf16x8 f;
      f[0] = (short)f2bf_rne(a.x * QSCALE); f[1] = (short)f2bf_rne(a.y * QSCALE);
      f[2] = (short)f2bf_rne(a.z * QSCALE); f[3] = (short)f2bf_rne(a.w * QSCALE);
      f[4] = (short)f2bf_rne(b.x * QSCALE); f[5] = (short)f2bf_rne(b.y * QSCALE);
      f[6] = (short)f2bf_rne(b.z * QSCALE); f[7] = (short)f2bf_rne(b.w * QSCALE);
      qf[s][j] = f;
    }
  }
  f32x4 acc[2][4]; f32x4 accl[2];
#pragma unroll
  for (int s = 0; s < 2; ++s) {
#pragma unroll
    for (int dt = 0; dt < 4; ++dt)
#pragma unroll
      for (int r = 0; r < 4; ++r) acc[s][dt][r] = 0.0f;
#pragma unroll
    for (int r = 0; r < 4; ++r) accl[s][r] = 0.0f;
  }
  bf16x4 vones;
  vones[0] = (short)0x3F80; vones[1] = (short)0x3F80;
  vones[2] = (short)0x3F80; vones[3] = (short)0x3F80;
  const f32x4 fz = {0.0f, 0.0f, 0.0f, 0.0f};
  auto load_mask = [&](int ti, unsigned long long m[2]) {
    if (mbits) {
#pragma unroll
      for (int s = 0; s < 2; ++s)
        m[s] = mbits[(size_t)ti * SQ + (q0 + s * 16 + col)];
    } else {
#pragma unroll
      for (int s = 0; s < 2; ++s) {
        int q = q0 + s * 16 + col;
        unsigned long long mm = 0;
#pragma unroll
        for (int j = 0; j < 4; ++j) {
          int4 mi = *(const int4*)(mraw + (size_t)q * SQ + ti * 64 + j * 16 + quad * 4);
          unsigned long long nib = (unsigned long long)((mi.x != 0) | ((mi.y != 0) << 1) |
                                                        ((mi.z != 0) << 2) | ((mi.w != 0) << 3));
          mm |= nib << (j * 16 + quad * 4);
        }
        m[s] = mm;
      }
    }
  };
  {
    const float4* kp = (const float4*)(Kb + (size_t)skk * DH + sd8);
    float4 k0 = kp[0], k1 = kp[1];
    const float* va = Vb + (size_t)(skp * 2) * DH + sd4;
    float4 v0 = *(const float4*)va, v1 = *(const float4*)(va + DH);
    uint4 kw;
    kw.x = pack_hi(k0.x, k0.y); kw.y = pack_hi(k0.z, k0.w);
    kw.z = pack_hi(k1.x, k1.y); kw.w = pack_hi(k1.z, k1.w);
    *(uint4*)&Klds[0][skk][sd8] = kw;
    Vtlds[0][sd4 + 0][skp] = pack_hi(v0.x, v1.x);
    Vtlds[0][sd4 + 1][skp] = pack_hi(v0.y, v1.y);
    Vtlds[0][sd4 + 2][skp] = pack_hi(v0.z, v1.z);
    Vtlds[0][sd4 + 3][skp] = pack_hi(v0.w, v1.w);
  }
  unsigned long long mcur[2];
  load_mask(0, mcur);
  for (int tile = 0; tile < 32; ++tile) {
    __syncthreads();
    const int cb = tile & 1, nb = cb ^ 1;
    const int tn = (tile + 1 < 32) ? tile + 1 : tile;
    const int kkn = tn * 64;
    const float4* kp = (const float4*)(Kb + (size_t)(kkn + skk) * DH + sd8);
    float4 k0 = kp[0], k1 = kp[1];
    const float* va = Vb + (size_t)(kkn + skp * 2) * DH + sd4;
    float4 v0 = *(const float4*)va;
    float4 v1 = *(const float4*)(va + DH);
    unsigned long long mnxt[2];
    load_mask(tn, mnxt);
    uint32_t pfw[2][4][2];
#pragma unroll
    for (int kt = 0; kt < 4; ++kt) {
      const bf16x8 kf0 = *(const bf16x8*)&Klds[cb][kt * 16 + col][quad * 8];
      const bf16x8 kf1 = *(const bf16x8*)&Klds[cb][kt * 16 + col][32 + quad * 8];
#pragma unroll
      for (int s = 0; s < 2; ++s) {
        f32x4 st = MFMA32(kf0, qf[s][0], fz);
        st = MFMA32(kf1, qf[s][1], st);
        uint32_t nib = (uint32_t)(mcur[s] >> (kt * 16 + quad * 4)) & 0xFu;
        float p[4];
#pragma unroll
        for (int r = 0; r < 4; ++r)
          p[r] = fast_exp2(((nib >> r) & 1u) ? -1.0e9f : st[r]);
        pfw[s][kt][0] = pack_hi(p[0], p[1]);
        pfw[s][kt][1] = pack_hi(p[2], p[3]);
      }
    }
    {
      uint4 kw;
      kw.x = pack_hi(k0.x, k0.y); kw.y = pack_hi(k0.z, k0.w);
      kw.z = pack_hi(k1.x, k1.y); kw.w = pack_hi(k1.z, k1.w);
      *(uint4*)&Klds[nb][skk][sd8] = kw;
      Vtlds[nb][sd4 + 0][skp] = pack_hi(v0.x, v1.x);
      Vtlds[nb][sd4 + 1][skp] = pack_hi(v0.y, v1.y);
      Vtlds[nb][sd4 + 2][skp] = pack_hi(v0.z, v1.z);
      Vtlds[nb][sd4 + 3][skp] = pack_hi(v0.w, v1.w);
    }
    mcur[0] = mnxt[0]; mcur[1] = mnxt[1];
#pragma unroll
    for (int kt = 0; kt < 4; ++kt) {
      union { uint32_t u[2]; bf16x4 v; } p0, p1;
      p0.u[0] = pfw[0][kt][0]; p0.u[1] = pfw[0][kt][1];
      p1.u[0] = pfw[1][kt][0]; p1.u[1] = pfw[1][kt][1];
      accl[0] = MFMA_PV16(vones, p0.v, accl[0]);
      accl[1] = MFMA_PV16(vones, p1.v, accl[1]);
#pragma unroll
      for (int dt = 0; dt < 4; ++dt) {
        union { uint2 u2; bf16x4 v; } cv;
        cv.u2 = *(const uint2*)&Vtlds[cb][dt * 16 + col][kt * 8 + quad * 2];
        acc[0][dt] = MFMA_PV16(cv.v, p0.v, acc[0][dt]);
        acc[1][dt] = MFMA_PV16(cv.v, p1.v, acc[1][dt]);
      }
    }
  }
#pragma unroll
  for (int s = 0; s < 2; ++s) {
    float inv = 1.0f / accl[s][0];
    int q = q0 + s * 16 + col;
    float* orow = Ob + (size_t)q * DH;
#pragma unroll
    for (int dt = 0; dt < 4; ++dt) {
      float4 o;
      o.x = acc[s][dt][0] * inv;
      o.y = acc[s][dt][1] * inv;
      o.z = acc[s][dt][2] * inv;
      o.w = acc[s][dt][3] * inv;
      *(float4*)(orow + dt * 16 + quad * 4) = o;
    }
  }
}

extern "C" void kernel_launch(void* const* d_in, const int* in_sizes, int n_in,
                              void* d_out, int out_size, void* d_ws, size_t ws_size,
                              hipStream_t stream) {
  const float* Q = (const float*)d_in[0];
  const float* K = (const float*)d_in[1];
  const float* V = (const float*)d_in[2];
  const int* mask = (const int*)d_in[3];
  float* out = (float*)d_out;

  const size_t PK_BYTES = (size_t)BH * 32 * 8192;      // 16 MB
  const size_t PV_BYTES = (size_t)BH * 32 * 8192;      // 16 MB
  const size_t PM_BYTES = (size_t)512 * 2048 * 8;      // 8 MB
  const size_t NEED_PACK = PK_BYTES + PV_BYTES + PM_BYTES;  // 40 MB
  const size_t OP_BYTES = (size_t)2 * BH * SQ * DH * 4;     // 67.1 MB
  const size_t LP_BYTES = (size_t)2 * BH * SQ * 4;          // 1 MB
  const size_t NEED_SPLIT = NEED_PACK + OP_BYTES + LP_BYTES;

  if (ws_size >= NEED_PACK) {
    uint4* pk = (uint4*)d_ws;
    uint4* pv = (uint4*)((char*)d_ws + PK_BYTES);
    uint2* pm = (uint2*)((char*)d_ws + PK_BYTES + PV_BYTES);
    pack_all<<<6144, 256, 0, stream>>>(K, V, mask, pk, pv, pm);
    if (ws_size >= NEED_SPLIT) {
      float* opart = (float*)((char*)d_ws + NEED_PACK);
      float* lpart = (float*)((char*)d_ws + NEED_PACK + OP_BYTES);
      attn4<<<1024, 256, 0, stream>>>((const uint8_t*)pk, (const uint8_t*)pv, pm,
                                      Q, opart, lpart, 16);
      norm_kernel<<<4096, 256, 0, stream>>>((const float4*)opart, lpart,
                                            (float4*)out);
    } else {
      attn4<<<512, 256, 0, stream>>>((const uint8_t*)pk, (const uint8_t*)pv, pm,
                                     Q, out, nullptr, 32);
    }
  } else if (ws_size >= (size_t)SQ * SQ / 8) {
    unsigned long long* bits = (unsigned long long*)d_ws;
    pack_mask_kernel<<<1024, 256, 0, stream>>>(mask, bits);
    attn_fb<<<512, 512, 0, stream>>>(Q, K, V, bits, mask, out);
  } else {
    attn_fb<<<512, 512, 0, stream>>>(Q, K, V, nullptr, mask, out);
  }
}